// Round 15
// baseline (205.327 us; speedup 1.0000x reference)
//
#include <hip/hip_runtime.h>
#include <cstdint>
#include <cstddef>

#define D 256
#define E 256
#define T 128
#define QIN 640   // D + E + T
#define P 8
#define R 16      // batch rows per block
#define KP 648    // qa row stride in ushort
#define DP 260    // qpre row stride in floats

typedef __attribute__((ext_vector_type(8))) short bf16x8;
typedef __attribute__((ext_vector_type(4))) float f32x4;

__device__ __forceinline__ ushort f2bf(float f) {   // RNE fp32->bf16
  uint32_t u = __float_as_uint(f);
  u += 0x7fffu + ((u >> 16) & 1u);
  return (ushort)(u >> 16);
}

__device__ __forceinline__ float rcpf(float x) { return __builtin_amdgcn_rcpf(x); }
__device__ __forceinline__ float rsqf(float x) { return __builtin_amdgcn_rsqf(x); }

__device__ __forceinline__ float fast_tanh(float x) {
  const float e = __expf(2.0f * x);
  return 1.0f - 2.0f * rcpf(e + 1.0f);
}

// 32-lane-group butterfly (offsets 16..1 stay within each 32-lane half)
__device__ __forceinline__ float rsum32(float v) {
#pragma unroll
  for (int o = 16; o > 0; o >>= 1) v += __shfl_xor(v, o, 64);
  return v;
}
__device__ __forceinline__ void rsum32_2(float& a, float& b) {
#pragma unroll
  for (int o = 16; o > 0; o >>= 1) {
    a += __shfl_xor(a, o, 64);
    b += __shfl_xor(b, o, 64);
  }
}

__device__ __forceinline__ float clampf(float x, float lo, float hi) {
  return fminf(fmaxf(x, lo), hi);
}

// W2[((k>>3)*D + n)*8 + (k&7)] = bf16(Wq[n][k])
__global__ void prep_w2_kernel(const float* __restrict__ Wq, ushort* __restrict__ W2) {
  const int idx = blockIdx.x * 256 + threadIdx.x;
  const int n = idx / QIN;
  const int k = idx - n * QIN;
  W2[((((k >> 3) * D + n) << 3)) + (k & 7)] = f2bf(Wq[idx]);
}

__device__ __forceinline__ bf16x8 cvt8(const float* p) {
  const float4 a = *(const float4*)p;
  const float4 b = *(const float4*)(p + 4);
  bf16x8 r;
  r[0] = (short)f2bf(a.x); r[1] = (short)f2bf(a.y);
  r[2] = (short)f2bf(a.z); r[3] = (short)f2bf(a.w);
  r[4] = (short)f2bf(b.x); r[5] = (short)f2bf(b.y);
  r[6] = (short)f2bf(b.z); r[7] = (short)f2bf(b.w);
  return r;
}

template <bool PRE>
__global__ __launch_bounds__(256, 4) void fused_kernel(
    const float* __restrict__ raw, const float* __restrict__ edge,
    const float* __restrict__ tim, const float* __restrict__ proto,
    const float* __restrict__ Wq, const ushort* __restrict__ W2,
    const float* __restrict__ bq, const float* __restrict__ Wg,
    const float* __restrict__ bg, const float* __restrict__ temp,
    const float* __restrict__ lnw, const float* __restrict__ lnb,
    float* __restrict__ out) {
  __shared__ ushort qa[R][KP];    // 20.25 KB
  __shared__ float qpre[R][DP];   // 16.25 KB

  const int tid = threadIdx.x;
  const int r0 = blockIdx.x * R;

  // ---- stage q_in rows -> bf16 LDS (coalesced float4 reads) ----
#pragma unroll
  for (int it = 0; it < (R * QIN / 4) / 256; ++it) {
    const int flat = it * 256 + tid;
    const int r = flat / (QIN / 4);
    const int p4 = (flat - r * (QIN / 4)) * 4;
    const size_t g = (size_t)(r0 + r);
    float4 v;
    if (p4 < D)          v = *(const float4*)(raw + g * D + p4);
    else if (p4 < D + E) v = *(const float4*)(edge + g * E + (p4 - D));
    else                 v = *(const float4*)(tim + g * T + (p4 - D - E));
    ushort4 hh;
    hh.x = f2bf(v.x); hh.y = f2bf(v.y); hh.z = f2bf(v.z); hh.w = f2bf(v.w);
    *(ushort4*)&qa[r][p4] = hh;
  }
  __syncthreads();

  const int w = tid >> 6;
  const int lane = tid & 63;
  const int lr = lane & 15;
  const int lh = lane >> 4;

  // ---- GEMM: 4 waves x 4 col-tiles of 16, K=640 in steps of 32 ----
  {
    f32x4 acc[4];
#pragma unroll
    for (int c = 0; c < 4; ++c) acc[c] = (f32x4){0.f, 0.f, 0.f, 0.f};

    for (int kb = 0; kb < QIN; kb += 32) {
      const bf16x8 af = *(const bf16x8*)&qa[lr][kb + lh * 8];
#pragma unroll
      for (int c = 0; c < 4; ++c) {
        const int n = w * 64 + c * 16 + lr;
        bf16x8 bv;
        if (PRE) {
          bv = *(const bf16x8*)&W2[(((kb >> 3) + lh) * D + n) << 3];
        } else {
          bv = cvt8(Wq + (size_t)n * QIN + kb + lh * 8);
        }
        acc[c] = __builtin_amdgcn_mfma_f32_16x16x32_bf16(af, bv, acc[c], 0, 0, 0);
      }
    }
    // C/D layout: col = lane&15, row = (lane>>4)*4 + reg
#pragma unroll
    for (int c = 0; c < 4; ++c) {
      const int n = w * 64 + c * 16 + lr;
      const float bqv = bq[n];
#pragma unroll
      for (int i = 0; i < 4; ++i) qpre[lh * 4 + i][n] = acc[c][i] + bqv;
    }
  }
  __syncthreads();

  // ---- epilogue: 2 rows per wave; j=1 burst issued inside j=0's tail ----
  const int h = lane >> 5;         // which row of the pair
  const int l32 = lane & 31;
  const int d0 = l32 * 4;          // dims [d0, d0+4)
  const int d1 = d0 + 128;         // dims [d1, d1+4)

  // hoisted per-lane constants (LN weights used twice per row)
  const float4 lw0 = *(const float4*)(lnw + d0);
  const float4 lw1 = *(const float4*)(lnw + d1);
  const float4 lb0 = *(const float4*)(lnb + d0);
  const float4 lb1 = *(const float4*)(lnb + d1);
  const float lwv[8] = {lw0.x, lw0.y, lw0.z, lw0.w, lw1.x, lw1.y, lw1.z, lw1.w};
  const float lbv[8] = {lb0.x, lb0.y, lb0.z, lb0.w, lb1.x, lb1.y, lb1.z, lb1.w};
  const float bgv = bg[0];
  const float invt = rcpf(clampf(temp[0], 0.5f, 5.0f) + 0.01f);

  // double-buffered proto/gate-input bursts (allocator rotates: A dies before B fills)
  float4 A0[P], A1[P], B0[P], B1[P];
  float4 raA0, raA1, t4A, raB0, raB1, t4B;

  // burst for j into (P0,P1,ra_0,ra_1,t_4)
  auto burst = [&](int j, float4* P0, float4* P1, float4& ra_0, float4& ra_1, float4& t_4) {
    const int r = j * 8 + w * 2 + h;
    const size_t g = (size_t)(r0 + r);
    const float* pb = proto + g * (size_t)(P * D);
#pragma unroll
    for (int p = 0; p < P; ++p) {
      P0[p] = *(const float4*)(pb + (size_t)p * D + d0);
      P1[p] = *(const float4*)(pb + (size_t)p * D + d1);
    }
    ra_0 = *(const float4*)(raw + g * D + d0);
    ra_1 = *(const float4*)(raw + g * D + d1);
    t_4  = *(const float4*)(tim + g * T + d0);
  };

  // per-iteration body; when PREF, issues the j=1 burst right after protos die
  auto body = [&](int j, const float4* P0, const float4* P1,
                  float4 ra_0, float4 ra_1, float4 t_4, bool pref) {
    const int r = j * 8 + w * 2 + h;
    const size_t g = (size_t)(r0 + r);

    // LN1 (batched moments) + tanh -> q[8]
    const float4 x0 = *(const float4*)&qpre[r][d0];
    const float4 x1 = *(const float4*)&qpre[r][d1];
    float x[8] = {x0.x, x0.y, x0.z, x0.w, x1.x, x1.y, x1.z, x1.w};
    float s = 0.f, ss = 0.f;
#pragma unroll
    for (int i = 0; i < 8; ++i) { s += x[i]; ss += x[i] * x[i]; }
    rsum32_2(s, ss);
    const float mu = s * (1.0f / 256.0f);
    const float var = ss * (1.0f / 256.0f) - mu * mu;
    const float rstd = rsqf(var + 1e-6f);
    float q[8];
    float qs = 0.f;
#pragma unroll
    for (int i = 0; i < 8; ++i) {
      q[i] = fast_tanh((x[i] - mu) * rstd * lwv[i] + lbv[i]);
      qs += q[i] * q[i];
    }

    // dot/norm partials for all 8 protos
    float dt[P], pn[P];
#pragma unroll
    for (int p = 0; p < P; ++p) {
      dt[p] = q[0] * P0[p].x + q[1] * P0[p].y + q[2] * P0[p].z + q[3] * P0[p].w +
              q[4] * P1[p].x + q[5] * P1[p].y + q[6] * P1[p].z + q[7] * P1[p].w;
      pn[p] = P0[p].x * P0[p].x + P0[p].y * P0[p].y + P0[p].z * P0[p].z +
              P0[p].w * P0[p].w + P1[p].x * P1[p].x + P1[p].y * P1[p].y +
              P1[p].z * P1[p].z + P1[p].w * P1[p].w;
    }
    // ONE batched butterfly: 17 chains (dt[8], pn[8], qs) x 5 steps
#pragma unroll
    for (int o = 16; o > 0; o >>= 1) {
#pragma unroll
      for (int p = 0; p < P; ++p) {
        dt[p] += __shfl_xor(dt[p], o, 64);
        pn[p] += __shfl_xor(pn[p], o, 64);
      }
      qs += __shfl_xor(qs, o, 64);
    }
    const float rq = fminf(rsqf(qs), 1e6f);   // 1/max(||q||,1e-6)

    // unnormalized online softmax + accumulate (sim in [-19.6,19.6], fp32-safe)
    float cv[8] = {0.f, 0.f, 0.f, 0.f, 0.f, 0.f, 0.f, 0.f};
    float us = 0.f;
#pragma unroll
    for (int p = 0; p < P; ++p) {
      const float rp = fminf(rsqf(pn[p]), 1e6f);
      const float sm = clampf(dt[p] * rq * rp, -10.0f, 10.0f) * invt;
      const float u = __expf(sm);
      us += u;
      cv[0] = fmaf(u, P0[p].x, cv[0]); cv[1] = fmaf(u, P0[p].y, cv[1]);
      cv[2] = fmaf(u, P0[p].z, cv[2]); cv[3] = fmaf(u, P0[p].w, cv[3]);
      cv[4] = fmaf(u, P1[p].x, cv[4]); cv[5] = fmaf(u, P1[p].y, cv[5]);
      cv[6] = fmaf(u, P1[p].z, cv[6]); cv[7] = fmaf(u, P1[p].w, cv[7]);
    }
    // ---- protos for this j are now dead: issue next j's burst HERE ----
    if (pref) burst(1, B0, B1, raB0, raB1, t4B);

    const float sinv = rcpf(us);
    float cd[8];
#pragma unroll
    for (int i = 0; i < 8; ++i) cd[i] = clampf(cv[i] * sinv, -5.0f, 5.0f);

    // gate (weights loaded here: short lifetimes, L1/L2-hot)
    const float rr[8] = {ra_0.x, ra_0.y, ra_0.z, ra_0.w, ra_1.x, ra_1.y, ra_1.z, ra_1.w};
    const float4 wr0 = *(const float4*)(Wg + d0);
    const float4 wr1 = *(const float4*)(Wg + d1);
    const float4 wc0 = *(const float4*)(Wg + D + d0);
    const float4 wc1 = *(const float4*)(Wg + D + d1);
    const float4 wt4 = *(const float4*)(Wg + 2 * D + d0);
    const float wrv[8] = {wr0.x, wr0.y, wr0.z, wr0.w, wr1.x, wr1.y, wr1.z, wr1.w};
    const float wcv[8] = {wc0.x, wc0.y, wc0.z, wc0.w, wc1.x, wc1.y, wc1.z, wc1.w};
    float gsum = clampf(t_4.x, -50.f, 50.f) * wt4.x + clampf(t_4.y, -50.f, 50.f) * wt4.y +
                 clampf(t_4.z, -50.f, 50.f) * wt4.z + clampf(t_4.w, -50.f, 50.f) * wt4.w;
#pragma unroll
    for (int i = 0; i < 8; ++i) {
      gsum += clampf(rr[i], -50.f, 50.f) * wrv[i];
      gsum += clampf(cd[i], -50.f, 50.f) * wcv[i];
    }
    const float z = clampf(rsum32(gsum) + bgv, -10.0f, 10.0f);
    const float gate = rcpf(1.0f + __expf(-z));

    // gated update + final LN (batched moments) + clip
    float upd[8];
    float s2 = 0.f, ss2 = 0.f;
#pragma unroll
    for (int i = 0; i < 8; ++i) {
      upd[i] = (1.0f - gate) * rr[i] + gate * cd[i];
      s2 += upd[i]; ss2 += upd[i] * upd[i];
    }
    rsum32_2(s2, ss2);
    const float mu2 = s2 * (1.0f / 256.0f);
    const float var2 = ss2 * (1.0f / 256.0f) - mu2 * mu2;
    const float rstd2 = rsqf(var2 + 1e-6f);
    float4 y0, y1;
    y0.x = clampf((upd[0] - mu2) * rstd2 * lwv[0] + lbv[0], -10.0f, 10.0f);
    y0.y = clampf((upd[1] - mu2) * rstd2 * lwv[1] + lbv[1], -10.0f, 10.0f);
    y0.z = clampf((upd[2] - mu2) * rstd2 * lwv[2] + lbv[2], -10.0f, 10.0f);
    y0.w = clampf((upd[3] - mu2) * rstd2 * lwv[3] + lbv[3], -10.0f, 10.0f);
    y1.x = clampf((upd[4] - mu2) * rstd2 * lwv[4] + lbv[4], -10.0f, 10.0f);
    y1.y = clampf((upd[5] - mu2) * rstd2 * lwv[5] + lbv[5], -10.0f, 10.0f);
    y1.z = clampf((upd[6] - mu2) * rstd2 * lwv[6] + lbv[6], -10.0f, 10.0f);
    y1.w = clampf((upd[7] - mu2) * rstd2 * lwv[7] + lbv[7], -10.0f, 10.0f);
    *(float4*)(out + g * D + d0) = y0;
    *(float4*)(out + g * D + d1) = y1;
  };

  burst(0, A0, A1, raA0, raA1, t4A);
  body(0, A0, A1, raA0, raA1, t4A, true);   // issues B-burst after A dies
  body(1, B0, B1, raB0, raB1, t4B, false);
}

extern "C" void kernel_launch(void* const* d_in, const int* in_sizes, int n_in,
                              void* d_out, int out_size, void* d_ws, size_t ws_size,
                              hipStream_t stream) {
  const float* raw   = (const float*)d_in[0];
  // d_in[1] = node_features: unused by the reference
  const float* edge  = (const float*)d_in[2];
  const float* tim   = (const float*)d_in[3];
  const float* proto = (const float*)d_in[4];
  const float* Wq    = (const float*)d_in[5];
  const float* bq    = (const float*)d_in[6];
  const float* Wg    = (const float*)d_in[7];
  const float* bg    = (const float*)d_in[8];
  const float* temp  = (const float*)d_in[9];
  const float* lnw   = (const float*)d_in[10];
  const float* lnb   = (const float*)d_in[11];
  float* out = (float*)d_out;

  const int B = in_sizes[0] / D;
  const int nblk = B / R;

  if (ws_size >= (size_t)QIN * D * sizeof(ushort)) {
    ushort* W2 = (ushort*)d_ws;
    prep_w2_kernel<<<(QIN * D) / 256, 256, 0, stream>>>(Wq, W2);
    fused_kernel<true><<<nblk, 256, 0, stream>>>(raw, edge, tim, proto, Wq, W2,
                                                 bq, Wg, bg, temp, lnw, lnb, out);
  } else {
    fused_kernel<false><<<nblk, 256, 0, stream>>>(raw, edge, tim, proto, Wq,
                                                  (const ushort*)nullptr, bq, Wg,
                                                  bg, temp, lnw, lnb, out);
  }
}

// Round 16
// 191.669 us; speedup vs baseline: 1.0713x; 1.0713x over previous
//
#include <hip/hip_runtime.h>
#include <cstdint>
#include <cstddef>

#define D 256
#define E 256
#define T 128
#define QIN 640   // D + E + T
#define P 8
#define R 16      // batch rows per block
#define KP 648    // qa row stride in ushort
#define DP 260    // qpre row stride in floats

typedef __attribute__((ext_vector_type(8))) short bf16x8;
typedef __attribute__((ext_vector_type(4))) float f32x4;

__device__ __forceinline__ ushort f2bf(float f) {   // RNE fp32->bf16
  uint32_t u = __float_as_uint(f);
  u += 0x7fffu + ((u >> 16) & 1u);
  return (ushort)(u >> 16);
}

__device__ __forceinline__ float rcpf(float x) { return __builtin_amdgcn_rcpf(x); }
__device__ __forceinline__ float rsqf(float x) { return __builtin_amdgcn_rsqf(x); }

__device__ __forceinline__ float fast_tanh(float x) {
  const float e = __expf(2.0f * x);
  return 1.0f - 2.0f * rcpf(e + 1.0f);
}

// 32-lane-group butterfly (offsets 16..1 stay within each 32-lane half)
__device__ __forceinline__ float rsum32(float v) {
#pragma unroll
  for (int o = 16; o > 0; o >>= 1) v += __shfl_xor(v, o, 64);
  return v;
}
__device__ __forceinline__ void rsum32_2(float& a, float& b) {
#pragma unroll
  for (int o = 16; o > 0; o >>= 1) {
    a += __shfl_xor(a, o, 64);
    b += __shfl_xor(b, o, 64);
  }
}

__device__ __forceinline__ float clampf(float x, float lo, float hi) {
  return fminf(fmaxf(x, lo), hi);
}

// W2[((k>>3)*D + n)*8 + (k&7)] = bf16(Wq[n][k])
__global__ void prep_w2_kernel(const float* __restrict__ Wq, ushort* __restrict__ W2) {
  const int idx = blockIdx.x * 256 + threadIdx.x;
  const int n = idx / QIN;
  const int k = idx - n * QIN;
  W2[((((k >> 3) * D + n) << 3)) + (k & 7)] = f2bf(Wq[idx]);
}

__device__ __forceinline__ bf16x8 cvt8(const float* p) {
  const float4 a = *(const float4*)p;
  const float4 b = *(const float4*)(p + 4);
  bf16x8 r;
  r[0] = (short)f2bf(a.x); r[1] = (short)f2bf(a.y);
  r[2] = (short)f2bf(a.z); r[3] = (short)f2bf(a.w);
  r[4] = (short)f2bf(b.x); r[5] = (short)f2bf(b.y);
  r[6] = (short)f2bf(b.z); r[7] = (short)f2bf(b.w);
  return r;
}

template <bool PRE>
__global__ __launch_bounds__(256, 4) void fused_kernel(
    const float* __restrict__ raw, const float* __restrict__ edge,
    const float* __restrict__ tim, const float* __restrict__ proto,
    const float* __restrict__ Wq, const ushort* __restrict__ W2,
    const float* __restrict__ bq, const float* __restrict__ Wg,
    const float* __restrict__ bg, const float* __restrict__ temp,
    const float* __restrict__ lnw, const float* __restrict__ lnb,
    float* __restrict__ out) {
  __shared__ ushort qa[R][KP];    // 20.25 KB
  __shared__ float qpre[R][DP];   // 16.25 KB

  const int tid = threadIdx.x;
  const int r0 = blockIdx.x * R;

  // ---- stage q_in rows -> bf16 LDS (coalesced float4 reads) ----
#pragma unroll
  for (int it = 0; it < (R * QIN / 4) / 256; ++it) {
    const int flat = it * 256 + tid;
    const int r = flat / (QIN / 4);
    const int p4 = (flat - r * (QIN / 4)) * 4;
    const size_t g = (size_t)(r0 + r);
    float4 v;
    if (p4 < D)          v = *(const float4*)(raw + g * D + p4);
    else if (p4 < D + E) v = *(const float4*)(edge + g * E + (p4 - D));
    else                 v = *(const float4*)(tim + g * T + (p4 - D - E));
    ushort4 hh;
    hh.x = f2bf(v.x); hh.y = f2bf(v.y); hh.z = f2bf(v.z); hh.w = f2bf(v.w);
    *(ushort4*)&qa[r][p4] = hh;
  }
  __syncthreads();

  const int w = tid >> 6;
  const int lane = tid & 63;
  const int lr = lane & 15;
  const int lh = lane >> 4;

  // ---- GEMM: 4 waves x 4 col-tiles of 16, K=640 in steps of 32 ----
  {
    f32x4 acc[4];
#pragma unroll
    for (int c = 0; c < 4; ++c) acc[c] = (f32x4){0.f, 0.f, 0.f, 0.f};

    for (int kb = 0; kb < QIN; kb += 32) {
      const bf16x8 af = *(const bf16x8*)&qa[lr][kb + lh * 8];
#pragma unroll
      for (int c = 0; c < 4; ++c) {
        const int n = w * 64 + c * 16 + lr;
        bf16x8 bv;
        if (PRE) {
          bv = *(const bf16x8*)&W2[(((kb >> 3) + lh) * D + n) << 3];
        } else {
          bv = cvt8(Wq + (size_t)n * QIN + kb + lh * 8);
        }
        acc[c] = __builtin_amdgcn_mfma_f32_16x16x32_bf16(af, bv, acc[c], 0, 0, 0);
      }
    }
    // C/D layout: col = lane&15, row = (lane>>4)*4 + reg
#pragma unroll
    for (int c = 0; c < 4; ++c) {
      const int n = w * 64 + c * 16 + lr;
      const float bqv = bq[n];
#pragma unroll
      for (int i = 0; i < 4; ++i) qpre[lh * 4 + i][n] = acc[c][i] + bqv;
    }
  }
  __syncthreads();

  // ---- epilogue: 2 rows per wave per pass (32-lane groups, coalesced halves) ----
  const int h = lane >> 5;         // which row of the pair
  const int l32 = lane & 31;
  const int d0 = l32 * 4;          // dims [d0, d0+4)
  const int d1 = d0 + 128;         // dims [d1, d1+4)

  // hoisted per-lane constants (LN weights used twice per row)
  const float4 lw0 = *(const float4*)(lnw + d0);
  const float4 lw1 = *(const float4*)(lnw + d1);
  const float4 lb0 = *(const float4*)(lnb + d0);
  const float4 lb1 = *(const float4*)(lnb + d1);
  const float lwv[8] = {lw0.x, lw0.y, lw0.z, lw0.w, lw1.x, lw1.y, lw1.z, lw1.w};
  const float lbv[8] = {lb0.x, lb0.y, lb0.z, lb0.w, lb1.x, lb1.y, lb1.z, lb1.w};
  const float bgv = bg[0];
  const float invt = rcpf(clampf(temp[0], 0.5f, 5.0f) + 0.01f);

#pragma unroll
  for (int j = 0; j < 2; ++j) {
    const int r = j * 8 + w * 2 + h;
    const size_t g = (size_t)(r0 + r);
    const float* pb = proto + g * (size_t)(P * D);

    // ---- ONE load burst: all 16 proto float4s + gate inputs (max MLP) ----
    float4 A0[P], A1[P];
#pragma unroll
    for (int p = 0; p < P; ++p) {
      A0[p] = *(const float4*)(pb + (size_t)p * D + d0);
      A1[p] = *(const float4*)(pb + (size_t)p * D + d1);
    }
    const float4 ra0 = *(const float4*)(raw + g * D + d0);
    const float4 ra1 = *(const float4*)(raw + g * D + d1);
    const float4 t4  = *(const float4*)(tim + g * T + d0);

    // LN1 (batched moments) + tanh -> q[8]  (overlaps proto load latency)
    const float4 x0 = *(const float4*)&qpre[r][d0];
    const float4 x1 = *(const float4*)&qpre[r][d1];
    float x[8] = {x0.x, x0.y, x0.z, x0.w, x1.x, x1.y, x1.z, x1.w};
    float s = 0.f, ss = 0.f;
#pragma unroll
    for (int i = 0; i < 8; ++i) { s += x[i]; ss += x[i] * x[i]; }
    rsum32_2(s, ss);
    const float mu = s * (1.0f / 256.0f);
    const float var = ss * (1.0f / 256.0f) - mu * mu;
    const float rstd = rsqf(var + 1e-6f);
    float q[8];
    float qs = 0.f;
#pragma unroll
    for (int i = 0; i < 8; ++i) {
      q[i] = fast_tanh((x[i] - mu) * rstd * lwv[i] + lbv[i]);
      qs += q[i] * q[i];
    }

    // dot/norm partials for all 8 protos (registers already resident)
    float dt[P], pn[P];
#pragma unroll
    for (int p = 0; p < P; ++p) {
      dt[p] = q[0] * A0[p].x + q[1] * A0[p].y + q[2] * A0[p].z + q[3] * A0[p].w +
              q[4] * A1[p].x + q[5] * A1[p].y + q[6] * A1[p].z + q[7] * A1[p].w;
      pn[p] = A0[p].x * A0[p].x + A0[p].y * A0[p].y + A0[p].z * A0[p].z +
              A0[p].w * A0[p].w + A1[p].x * A1[p].x + A1[p].y * A1[p].y +
              A1[p].z * A1[p].z + A1[p].w * A1[p].w;
    }
    // ONE batched butterfly: 17 chains (dt[8], pn[8], qs) x 5 steps
#pragma unroll
    for (int o = 16; o > 0; o >>= 1) {
#pragma unroll
      for (int p = 0; p < P; ++p) {
        dt[p] += __shfl_xor(dt[p], o, 64);
        pn[p] += __shfl_xor(pn[p], o, 64);
      }
      qs += __shfl_xor(qs, o, 64);
    }
    const float rq = fminf(rsqf(qs), 1e6f);   // 1/max(||q||,1e-6)

    // unnormalized online softmax + accumulate (sim in [-19.6,19.6], fp32-safe)
    float cv[8] = {0.f, 0.f, 0.f, 0.f, 0.f, 0.f, 0.f, 0.f};
    float us = 0.f;
#pragma unroll
    for (int p = 0; p < P; ++p) {
      const float rp = fminf(rsqf(pn[p]), 1e6f);
      const float sm = clampf(dt[p] * rq * rp, -10.0f, 10.0f) * invt;
      const float u = __expf(sm);
      us += u;
      cv[0] = fmaf(u, A0[p].x, cv[0]); cv[1] = fmaf(u, A0[p].y, cv[1]);
      cv[2] = fmaf(u, A0[p].z, cv[2]); cv[3] = fmaf(u, A0[p].w, cv[3]);
      cv[4] = fmaf(u, A1[p].x, cv[4]); cv[5] = fmaf(u, A1[p].y, cv[5]);
      cv[6] = fmaf(u, A1[p].z, cv[6]); cv[7] = fmaf(u, A1[p].w, cv[7]);
    }
    const float sinv = rcpf(us);
    float cd[8];
#pragma unroll
    for (int i = 0; i < 8; ++i) cd[i] = clampf(cv[i] * sinv, -5.0f, 5.0f);

    // gate (weights loaded here: short lifetimes, L1/L2-hot)
    const float rr[8] = {ra0.x, ra0.y, ra0.z, ra0.w, ra1.x, ra1.y, ra1.z, ra1.w};
    const float4 wr0 = *(const float4*)(Wg + d0);
    const float4 wr1 = *(const float4*)(Wg + d1);
    const float4 wc0 = *(const float4*)(Wg + D + d0);
    const float4 wc1 = *(const float4*)(Wg + D + d1);
    const float4 wt4 = *(const float4*)(Wg + 2 * D + d0);
    const float wrv[8] = {wr0.x, wr0.y, wr0.z, wr0.w, wr1.x, wr1.y, wr1.z, wr1.w};
    const float wcv[8] = {wc0.x, wc0.y, wc0.z, wc0.w, wc1.x, wc1.y, wc1.z, wc1.w};
    float gsum = clampf(t4.x, -50.f, 50.f) * wt4.x + clampf(t4.y, -50.f, 50.f) * wt4.y +
                 clampf(t4.z, -50.f, 50.f) * wt4.z + clampf(t4.w, -50.f, 50.f) * wt4.w;
#pragma unroll
    for (int i = 0; i < 8; ++i) {
      gsum += clampf(rr[i], -50.f, 50.f) * wrv[i];
      gsum += clampf(cd[i], -50.f, 50.f) * wcv[i];
    }
    const float z = clampf(rsum32(gsum) + bgv, -10.0f, 10.0f);
    const float gate = rcpf(1.0f + __expf(-z));

    // gated update + final LN (batched moments) + clip
    float upd[8];
    float s2 = 0.f, ss2 = 0.f;
#pragma unroll
    for (int i = 0; i < 8; ++i) {
      upd[i] = (1.0f - gate) * rr[i] + gate * cd[i];
      s2 += upd[i]; ss2 += upd[i] * upd[i];
    }
    rsum32_2(s2, ss2);
    const float mu2 = s2 * (1.0f / 256.0f);
    const float var2 = ss2 * (1.0f / 256.0f) - mu2 * mu2;
    const float rstd2 = rsqf(var2 + 1e-6f);
    float4 y0, y1;
    y0.x = clampf((upd[0] - mu2) * rstd2 * lwv[0] + lbv[0], -10.0f, 10.0f);
    y0.y = clampf((upd[1] - mu2) * rstd2 * lwv[1] + lbv[1], -10.0f, 10.0f);
    y0.z = clampf((upd[2] - mu2) * rstd2 * lwv[2] + lbv[2], -10.0f, 10.0f);
    y0.w = clampf((upd[3] - mu2) * rstd2 * lwv[3] + lbv[3], -10.0f, 10.0f);
    y1.x = clampf((upd[4] - mu2) * rstd2 * lwv[4] + lbv[4], -10.0f, 10.0f);
    y1.y = clampf((upd[5] - mu2) * rstd2 * lwv[5] + lbv[5], -10.0f, 10.0f);
    y1.z = clampf((upd[6] - mu2) * rstd2 * lwv[6] + lbv[6], -10.0f, 10.0f);
    y1.w = clampf((upd[7] - mu2) * rstd2 * lwv[7] + lbv[7], -10.0f, 10.0f);
    *(float4*)(out + g * D + d0) = y0;
    *(float4*)(out + g * D + d1) = y1;
  }
}

extern "C" void kernel_launch(void* const* d_in, const int* in_sizes, int n_in,
                              void* d_out, int out_size, void* d_ws, size_t ws_size,
                              hipStream_t stream) {
  const float* raw   = (const float*)d_in[0];
  // d_in[1] = node_features: unused by the reference
  const float* edge  = (const float*)d_in[2];
  const float* tim   = (const float*)d_in[3];
  const float* proto = (const float*)d_in[4];
  const float* Wq    = (const float*)d_in[5];
  const float* bq    = (const float*)d_in[6];
  const float* Wg    = (const float*)d_in[7];
  const float* bg    = (const float*)d_in[8];
  const float* temp  = (const float*)d_in[9];
  const float* lnw   = (const float*)d_in[10];
  const float* lnb   = (const float*)d_in[11];
  float* out = (float*)d_out;

  const int B = in_sizes[0] / D;
  const int nblk = B / R;

  if (ws_size >= (size_t)QIN * D * sizeof(ushort)) {
    ushort* W2 = (ushort*)d_ws;
    prep_w2_kernel<<<(QIN * D) / 256, 256, 0, stream>>>(Wq, W2);
    fused_kernel<true><<<nblk, 256, 0, stream>>>(raw, edge, tim, proto, Wq, W2,
                                                 bq, Wg, bg, temp, lnw, lnb, out);
  } else {
    fused_kernel<false><<<nblk, 256, 0, stream>>>(raw, edge, tim, proto, Wq,
                                                  (const ushort*)nullptr, bq, Wg,
                                                  bg, temp, lnw, lnb, out);
  }
}